// Round 21
// baseline (219.549 us; speedup 1.0000x reference)
//
#include <hip/hip_runtime.h>

constexpr int NN = 100000;
constexpr int NE = 1600000;
constexpr int IN_DIM = 300;
constexpr int HID = 128;
constexpr int NA = 2048;
constexpr int NF_CAP = 50000;   // frontier cap (expected ~29K for this input)
constexpr int G1_BLOCKS = 391;  // ceil(782/2): GEMM1 half-grid per fused dispatch
constexpr int EDGE_BLOCKS = 3125;  // NE / 512 exactly

using short8 = __attribute__((ext_vector_type(8))) short;
using f32x4  = __attribute__((ext_vector_type(4))) float;

__device__ inline unsigned short f2bf(float x) {
    unsigned u = __float_as_uint(x);
    unsigned r = u + 0x7FFFu + ((u >> 16) & 1u);
    return (unsigned short)(r >> 16);
}
__device__ inline float bf2f(unsigned short h) {
    return __uint_as_float(((unsigned)h) << 16);
}

__device__ inline void gload_lds16(const void* g, void* l) {
    __builtin_amdgcn_global_load_lds(
        (const __attribute__((address_space(1))) unsigned int*)g,
        (__attribute__((address_space(3))) unsigned int*)l, 16, 0, 0);
}

// ---------------- aspect flags ----------------
__global__ void k_flag2(const int* __restrict__ asp, unsigned char* __restrict__ flags2,
                        int* __restrict__ flags1) {
    int i = blockIdx.x * blockDim.x + threadIdx.x;
    if (i < NA) {
        int n = asp[i];
        flags2[n] = 1;
        flags1[n] = 1;
    }
}

// ---------------- fused dual hierarchical exclusive scan (+ dis) ----------------
__global__ __launch_bounds__(1024) void k_scan2_local(const int* __restrict__ degi,
                                                      const int* __restrict__ flags1,
                                                      int* __restrict__ off,
                                                      int* __restrict__ off2,
                                                      int* __restrict__ blksum,
                                                      int* __restrict__ blksum2,
                                                      float* __restrict__ dis) {
    __shared__ int sh[1024];
    __shared__ int sh2[1024];
    int t = threadIdx.x;
    int base = blockIdx.x * 1024;
    int ok = (base + t < NN);
    int f = ok ? flags1[base + t] : 0;
    int d = ok ? degi[base + t] : 0;
    int v = f ? d : 0;
    if (ok) dis[base + t] = rsqrtf((float)d + 1.0f);   // +1 self loop (folded k_dis)
    sh[t] = v;
    sh2[t] = f;
    __syncthreads();
    for (int s = 1; s < 1024; s <<= 1) {
        int a = (t >= s) ? sh[t - s] : 0;
        int a2 = (t >= s) ? sh2[t - s] : 0;
        __syncthreads();
        sh[t] += a;
        sh2[t] += a2;
        __syncthreads();
    }
    if (ok) {
        off[base + t] = sh[t] - v;
        off2[base + t] = sh2[t] - f;
    }
    if (t == 1023) {
        blksum[blockIdx.x] = sh[1023];
        blksum2[blockIdx.x] = sh2[1023];
    }
}

__global__ __launch_bounds__(128) void k_scan2_blk(int* __restrict__ blksum,
                                                   int* __restrict__ blksum2, int nb) {
    __shared__ int sh[128];
    __shared__ int sh2[128];
    int t = threadIdx.x;
    int v = (t < nb) ? blksum[t] : 0;
    int v2 = (t < nb) ? blksum2[t] : 0;
    sh[t] = v;
    sh2[t] = v2;
    __syncthreads();
    for (int s = 1; s < 128; s <<= 1) {
        int a = (t >= s) ? sh[t - s] : 0;
        int a2 = (t >= s) ? sh2[t - s] : 0;
        __syncthreads();
        sh[t] += a;
        sh2[t] += a2;
        __syncthreads();
    }
    if (t < nb) {
        blksum[t] = sh[t] - v;
        blksum2[t] = sh2[t] - v2;
    }
}

// scan finalize + compact (folded k_compact)
__global__ void k_scan2_add(int* __restrict__ off, int* __restrict__ off2,
                            const int* __restrict__ blksum, const int* __restrict__ blksum2,
                            const int* __restrict__ flags1,
                            int* __restrict__ list, int* __restrict__ remap,
                            int* __restrict__ nf) {
    int i = blockIdx.x * blockDim.x + threadIdx.x;
    if (i < NN) {
        off[i] += blksum[i >> 10];
        int o2 = off2[i] + blksum2[i >> 10];
        off2[i] = o2;
        int f = flags1[i];
        if (f && o2 < NF_CAP) {
            list[o2] = i;
            remap[i] = o2;
        }
        if (i == NN - 1) {
            int tot = o2 + f;
            *nf = (tot < NF_CAP) ? tot : NF_CAP;
        }
    }
}

// ---------------- B pre-pack: fragment-ordered 16KB tile images ----------------
__global__ void k_prepB(const float* __restrict__ B, unsigned short* __restrict__ img,
                        int K, int NT) {
    int i = blockIdx.x * blockDim.x + threadIdx.x;
    if (i >= NT * 4096) return;
    int kt = i >> 12;
    int rem = i & 4095;
    int ct = rem >> 9;
    int s = rem & 511;          // lg*128 + lr*8 + j
    int lg = s >> 7;
    int lr = (s >> 3) & 15;
    int j = s & 7;
    int k = kt * 32 + lg * 8 + j;
    int col = ct * 16 + lr;
    float v = (k < K) ? B[k * 128 + col] : 0.f;
    unsigned short hi = f2bf(v);
    unsigned short lo = f2bf(v - bf2f(hi));
    img[kt * 8192 + ct * 1024 + s] = hi;
    img[kt * 8192 + ct * 1024 + 512 + s] = lo;
}

// ---------------- split-bf16 MFMA GEMM device body (round-14 structure) ----------------
// 128x128 tile, 8 waves (512 thr), wave owns 16 rows. B fragment-image DMA via
// global_load_lds (lane-linear, conflict-free, measured 0), 1-kt 32KB dbuf;
// A per-lane direct global, reg dbuf; one barrier per kt. Best measured form
// (rounds 13-20: five distinct restructures all neutral or regressed).
template <int K, int NT>
__device__ __forceinline__ void gemm_dev(int gbid, const float* __restrict__ A,
        const unsigned short* __restrict__ Bimg,
        float* __restrict__ C, int M, const int* __restrict__ Mptr) {
    __shared__ alignas(16) unsigned short ldsB[2][8192];   // 2 x 16KB
    const int Mv = Mptr ? *Mptr : M;
    const int row0 = gbid * 128;
    if (row0 >= Mv) return;
    const int t = threadIdx.x;
    const int w = t >> 6;       // 0..7
    const int l = t & 63;
    const int lr = l & 15;
    const int lg = l >> 4;

    const int r0 = row0 + w * 16 + lr;
    const long a0 = (long)(r0 < Mv ? r0 : Mv - 1) * K + lg * 8;   // clamp loads, guard stores

    f32x4 acc[8];
#pragma unroll
    for (int ct = 0; ct < 8; ++ct) acc[ct] = (f32x4){0.f, 0.f, 0.f, 0.f};

    float4 A0[2], A1[2];   // A fragment double-buffer; literal indices only

    auto LOADA = [&](float4* buf, int kt) {
        const int k0 = kt * 32 + lg * 8;
        const float* s0 = A + a0 + kt * 32;
        if (k0 + 8 <= K) {
            buf[0] = *(const float4*)(s0);
            buf[1] = *(const float4*)(s0 + 4);
        } else {
            float t0[8];
#pragma unroll
            for (int j = 0; j < 8; ++j) t0[j] = (k0 + j < K) ? s0[j] : 0.f;
            buf[0] = make_float4(t0[0], t0[1], t0[2], t0[3]);
            buf[1] = make_float4(t0[4], t0[5], t0[6], t0[7]);
        }
    };

    auto STAGE_B = [&](int buf, int kt) {   // 8 waves x 2KB = 16KB, lane-linear
        const char* g = (const char*)Bimg + (long)kt * 16384 + w * 2048 + l * 16;
        gload_lds16(g, &ldsB[buf][w * 1024]);
        gload_lds16(g + 1024, &ldsB[buf][w * 1024 + 512]);
    };

    auto CONV = [&](const float4* buf, short8& h0, short8& e0) {
        float v0[8] = {buf[0].x, buf[0].y, buf[0].z, buf[0].w, buf[1].x, buf[1].y, buf[1].z, buf[1].w};
#pragma unroll
        for (int j = 0; j < 8; ++j) {
            unsigned short hi = f2bf(v0[j]);
            h0[j] = (short)hi;
            e0[j] = (short)f2bf(v0[j] - bf2f(hi));
        }
    };

    auto COMPUTE = [&](const unsigned short* bbuf, short8 ah, short8 al) {
#pragma unroll
        for (int ct = 0; ct < 8; ++ct) {
            const unsigned short* bp = bbuf + ct * 1024 + lg * 128 + lr * 8;   // lane-linear: conflict-free
            short8 bh = *(const short8*)(bp);
            short8 bl = *(const short8*)(bp + 512);
            acc[ct] = __builtin_amdgcn_mfma_f32_16x16x32_bf16(ah, bh, acc[ct], 0, 0, 0);
            acc[ct] = __builtin_amdgcn_mfma_f32_16x16x32_bf16(al, bh, acc[ct], 0, 0, 0);
            acc[ct] = __builtin_amdgcn_mfma_f32_16x16x32_bf16(ah, bl, acc[ct], 0, 0, 0);
        }
    };

    LOADA(A0, 0);
    STAGE_B(0, 0);
    __syncthreads();   // compiler drains vmcnt before barrier -> buf0 ready
    for (int kt = 0; kt < NT; kt += 2) {
        if (kt + 1 < NT) {
            LOADA(A1, kt + 1);      // next A in flight under compute
            STAGE_B(1, kt + 1);     // next B DMA in flight under compute
        }
        {
            short8 h0, e0;
            CONV(A0, h0, e0);
            COMPUTE(ldsB[0], h0, e0);
        }
        __syncthreads();            // buf1 staged + buf0 reads done
        if (kt + 1 < NT) {
            if (kt + 2 < NT) {
                LOADA(A0, kt + 2);
                STAGE_B(0, kt + 2);
            }
            short8 h0, e0;
            CONV(A1, h0, e0);
            COMPUTE(ldsB[1], h0, e0);
            __syncthreads();
        }
    }
    // C/D layout: col = lane&15, row = (lane>>4)*4 + reg
#pragma unroll
    for (int ct = 0; ct < 8; ++ct)
#pragma unroll
        for (int r = 0; r < 4; ++r) {
            int row = row0 + w * 16 + lg * 4 + r;
            if (row < Mv) C[(long)row * 128 + ct * 16 + lr] = acc[ct][r];
        }
}

// ---------------- fused dispatch A: deg_mark (blocks 0..EDGE) then GEMM1 half ----------------
// EDGE BLOCKS FIRST: they are short and retire in ~30us, freeing CUs so the
// latency-bound GEMM blocks run on a quiet memory subsystem (round 15-20
// measured fused=88us >> 36+30 standalone sum = atomic-storm interference).
__global__ __launch_bounds__(512, 4) void k_fusedA(const float* __restrict__ A,
        const unsigned short* __restrict__ Bimg, float* __restrict__ C,
        const int* __restrict__ src, const int* __restrict__ dst,
        const unsigned char* __restrict__ flags2,
        int* __restrict__ degi, int* __restrict__ flags1) {
    if (blockIdx.x >= EDGE_BLOCKS) {
        gemm_dev<IN_DIM, 10>(blockIdx.x - EDGE_BLOCKS, A, Bimg, C, NN, nullptr);
    } else {
        int e = blockIdx.x * 512 + threadIdx.x;
        if (e < NE) {
            int d = dst[e];
            atomicAdd(&degi[d], 1);
            if (flags2[d]) flags1[src[e]] = 1;
        }
    }
}

// ---------------- fused dispatch B: filtered fill (blocks 0..EDGE) then GEMM1 half ----------------
__global__ __launch_bounds__(512, 4) void k_fusedB(const float* __restrict__ A,
        const unsigned short* __restrict__ Bimg, float* __restrict__ C,
        const int* __restrict__ src, const int* __restrict__ dst,
        const int* __restrict__ flags1,
        int* __restrict__ off, int* __restrict__ csr) {
    if (blockIdx.x >= EDGE_BLOCKS) {
        gemm_dev<IN_DIM, 10>(blockIdx.x - EDGE_BLOCKS + G1_BLOCKS, A, Bimg, C, NN, nullptr);
    } else {
        int e = blockIdx.x * 512 + threadIdx.x;
        if (e < NE) {
            int d = dst[e];
            if (flags1[d]) {
                int pos = atomicAdd(&off[d], 1);
                csr[pos] = src[e];
            }
        }
    }
}

// ---------------- GEMM2 (frontier rows) ----------------
__global__ __launch_bounds__(512, 4) void k_gemm2(const float* __restrict__ A,
        const unsigned short* __restrict__ Bimg, float* __restrict__ C,
        const int* __restrict__ nf) {
    gemm_dev<HID, 4>(blockIdx.x, A, Bimg, C, 0, nf);
}

// ---------------- gather layer 1: half-wave edge-parallel, float4, x2 unroll ----------------
__global__ __launch_bounds__(256) void k_gather1(const int* __restrict__ list,
                                                 const int* __restrict__ nf,
                                                 const int* __restrict__ csr,
                                                 const int* __restrict__ offpost,
                                                 const float* __restrict__ dis,
                                                 const float* __restrict__ h1,
                                                 const float* __restrict__ b1,
                                                 float* __restrict__ out) {
    int wave = threadIdx.x >> 6;
    int lane = threadIdx.x & 63;
    int half = lane >> 5;
    int sl = lane & 31;
    int idx = blockIdx.x * 4 + wave;
    if (idx >= *nf) return;
    int n = list[idx];
    int start = (n == 0) ? 0 : offpost[n - 1];
    int end = offpost[n];
    float dn = dis[n];
    float ax = 0.f, ay = 0.f, az = 0.f, aw = 0.f;
    int i = start + half;
    for (; i + 2 < end; i += 4) {          // two edges per half per trip
        int s0 = csr[i], s1 = csr[i + 2];
        float w0 = dis[s0], w1 = dis[s1];
        float4 v0 = *(const float4*)&h1[(long)s0 * HID + sl * 4];
        float4 v1 = *(const float4*)&h1[(long)s1 * HID + sl * 4];
        ax += w0 * v0.x + w1 * v1.x;
        ay += w0 * v0.y + w1 * v1.y;
        az += w0 * v0.z + w1 * v1.z;
        aw += w0 * v0.w + w1 * v1.w;
    }
    if (i < end) {
        int s = csr[i];
        float wgt = dis[s];
        float4 v = *(const float4*)&h1[(long)s * HID + sl * 4];
        ax += wgt * v.x;
        ay += wgt * v.y;
        az += wgt * v.z;
        aw += wgt * v.w;
    }
    ax += __shfl_xor(ax, 32);
    ay += __shfl_xor(ay, 32);
    az += __shfl_xor(az, 32);
    aw += __shfl_xor(aw, 32);
    if (half == 0) {
        float4 hv = *(const float4*)&h1[(long)n * HID + sl * 4];
        float4 bv = *(const float4*)&b1[sl * 4];
        float4 r;
        r.x = fmaxf(dn * (ax + dn * hv.x) + bv.x, 0.f);
        r.y = fmaxf(dn * (ay + dn * hv.y) + bv.y, 0.f);
        r.z = fmaxf(dn * (az + dn * hv.z) + bv.z, 0.f);
        r.w = fmaxf(dn * (aw + dn * hv.w) + bv.w, 0.f);
        *reinterpret_cast<float4*>(&out[(long)idx * HID + sl * 4]) = r;
    }
}

// ---------------- gather layer 2 (aspects, remapped) + classifier ----------------
__global__ __launch_bounds__(256) void k_gather2(const int* __restrict__ asp,
                                                 const int* __restrict__ remap,
                                                 const int* __restrict__ csr,
                                                 const int* __restrict__ offpost,
                                                 const float* __restrict__ dis,
                                                 const float* __restrict__ t2,
                                                 const float* __restrict__ b2,
                                                 const float* __restrict__ Wc,
                                                 const float* __restrict__ bc,
                                                 float* __restrict__ out) {
    int wave = threadIdx.x >> 6;
    int lane = threadIdx.x & 63;
    int a = blockIdx.x * 4 + wave;
    if (a >= NA) return;
    int n = asp[a];
    int start = (n == 0) ? 0 : offpost[n - 1];
    int end = offpost[n];
    float dn = dis[n];
    float ax = 0.f, ay = 0.f;
    int i = start;
    for (; i + 4 <= end; i += 4) {
        int s0 = csr[i], s1 = csr[i + 1], s2 = csr[i + 2], s3 = csr[i + 3];
        float w0 = dis[s0], w1 = dis[s1], w2 = dis[s2], w3 = dis[s3];
        int r0 = remap[s0], r1 = remap[s1], r2 = remap[s2], r3 = remap[s3];
        float2 v0 = *(const float2*)&t2[(long)r0 * HID + lane * 2];
        float2 v1 = *(const float2*)&t2[(long)r1 * HID + lane * 2];
        float2 v2 = *(const float2*)&t2[(long)r2 * HID + lane * 2];
        float2 v3 = *(const float2*)&t2[(long)r3 * HID + lane * 2];
        ax += w0 * v0.x + w1 * v1.x + w2 * v2.x + w3 * v3.x;
        ay += w0 * v0.y + w1 * v1.y + w2 * v2.y + w3 * v3.y;
    }
    for (; i < end; ++i) {
        int s = csr[i];
        float w = dis[s];
        float2 v = *(const float2*)&t2[(long)remap[s] * HID + lane * 2];
        ax += w * v.x;
        ay += w * v.y;
    }
    float2 hv = *(const float2*)&t2[(long)remap[n] * HID + lane * 2];
    float vx = dn * (ax + dn * hv.x) + b2[2 * lane];
    float vy = dn * (ay + dn * hv.y) + b2[2 * lane + 1];
    float l0 = vx * Wc[(2 * lane) * 3 + 0] + vy * Wc[(2 * lane + 1) * 3 + 0];
    float l1 = vx * Wc[(2 * lane) * 3 + 1] + vy * Wc[(2 * lane + 1) * 3 + 1];
    float l2 = vx * Wc[(2 * lane) * 3 + 2] + vy * Wc[(2 * lane + 1) * 3 + 2];
#pragma unroll
    for (int s = 32; s > 0; s >>= 1) {
        l0 += __shfl_xor(l0, s);
        l1 += __shfl_xor(l1, s);
        l2 += __shfl_xor(l2, s);
    }
    if (lane == 0) {
        out[a * 3 + 0] = l0 + bc[0];
        out[a * 3 + 1] = l1 + bc[1];
        out[a * 3 + 2] = l2 + bc[2];
    }
}

extern "C" void kernel_launch(void* const* d_in, const int* in_sizes, int n_in,
                              void* d_out, int out_size, void* d_ws, size_t ws_size,
                              hipStream_t stream) {
    const float* features = (const float*)d_in[0];
    const int* ei = (const int*)d_in[1];
    const int* src = ei;
    const int* dst = ei + NE;
    const int* asp = (const int*)d_in[2];
    const float* W1 = (const float*)d_in[3];
    const float* b1 = (const float*)d_in[4];
    const float* W2 = (const float*)d_in[5];
    const float* b2 = (const float*)d_in[6];
    const float* Wc = (const float*)d_in[7];
    const float* bc = (const float*)d_in[8];
    float* out = (float*)d_out;

    char* ws = (char*)d_ws;
    float* dis   = (float*)(ws + 0);                        // 400000
    unsigned short* bimg1 = (unsigned short*)(ws + 400384); // 163840
    unsigned short* bimg2 = (unsigned short*)(ws + 400384 + 163840); // 65536
    int*   off   = (int*)  (ws + 800768);                   // 400000 (filtered CSR offsets -> offpost)
    int*   blksum  = (int*)(ws + 1201152);                  // 1024
    int*   blksum2 = (int*)(ws + 1202176);                  // 1024
    int*   nf    = (int*)  (ws + 1203200);                  // 128
    int*   csr   = (int*)  (ws + 1203328);                  // 6400000 (ends 7603328)
    int*   flags1= (int*)  (ws + 7603328);                  // 400000
    int*   off2  = (int*)  (ws + 8003328);                  // 400000
    int*   list  = (int*)  (ws + 8403328);                  // 400000
    int*   remap = (int*)  (ws + 8803328);                  // 400000 (ends 9203328)
    float* bufA  = (float*)(ws + 9203328);                  // 51200000 (h1, then t2_c)
    float* bufB  = (float*)(ws + 60403328);                 // 25600000 (h2in_c)
    int*   degi  = (int*)  (ws + 60403328);                 // aliases bufB head: degi is
                                                            //  dead before gather1 writes bufB
    unsigned char* flags2 = (unsigned char*)(ws + 86003328);// 100000

    const int NB = (NN + 1023) / 1024;  // 98

    // prologue: flags, degree init, B pre-pack (all independent of edge pass)
    hipMemsetAsync(degi, 0, NN * sizeof(int), stream);
    hipMemsetAsync(flags1, 0, NN * sizeof(int), stream);
    hipMemsetAsync(flags2, 0, NN, stream);
    k_flag2<<<(NA + 255) / 256, 256, 0, stream>>>(asp, flags2, flags1);
    k_prepB<<<(10 * 4096 + 255) / 256, 256, 0, stream>>>(W1, bimg1, IN_DIM, 10);
    k_prepB<<<(4 * 4096 + 255) / 256, 256, 0, stream>>>(W2, bimg2, HID, 4);

    // dispatch A: deg_mark edge pass (first) ∥ GEMM1 first half (after)
    k_fusedA<<<EDGE_BLOCKS + G1_BLOCKS, 512, 0, stream>>>(
        features, bimg1, bufA, src, dst, flags2, degi, flags1);

    // scans (dis folded into local; compact folded into add)
    k_scan2_local<<<NB, 1024, 0, stream>>>(degi, flags1, off, off2, blksum, blksum2, dis);
    k_scan2_blk<<<1, 128, 0, stream>>>(blksum, blksum2, NB);
    k_scan2_add<<<(NN + 255) / 256, 256, 0, stream>>>(off, off2, blksum, blksum2,
                                                      flags1, list, remap, nf);

    // dispatch B: filtered CSR fill (first) ∥ GEMM1 second half (after)
    k_fusedB<<<EDGE_BLOCKS + G1_BLOCKS, 512, 0, stream>>>(
        features, bimg1, bufA, src, dst, flags1, off, csr);

    // layer-1 aggregation (frontier) -> compacted h2in
    k_gather1<<<(NF_CAP + 3) / 4, 256, 0, stream>>>(list, nf, csr, off, dis, bufA, b1, bufB);

    // layer 2: t2_c = h2in_c@W2 (frontier rows); logits per aspect
    k_gemm2<<<(NF_CAP + 127) / 128, 512, 0, stream>>>(bufB, bimg2, bufA, nf);
    k_gather2<<<(NA + 3) / 4, 256, 0, stream>>>(asp, remap, csr, off, dis, bufA, b2, Wc, bc, out);
}

// Round 22
// 202.086 us; speedup vs baseline: 1.0864x; 1.0864x over previous
//
#include <hip/hip_runtime.h>

constexpr int NN = 100000;
constexpr int NE = 1600000;
constexpr int IN_DIM = 300;
constexpr int HID = 128;
constexpr int NA = 2048;
constexpr int NF_CAP = 50000;   // frontier cap (expected ~29K for this input)
constexpr int G1_BLOCKS = 391;  // ceil(782/2): GEMM1 half-grid per fused dispatch
constexpr int EDGE_SLOTS = 3125;   // NE / 512 exactly
constexpr int FUSE_GROUPS = 782;   // ceil(EDGE_SLOTS/4): groups of 8 blocks (4 gemm-lane, 4 edge-lane)

using short8 = __attribute__((ext_vector_type(8))) short;
using f32x4  = __attribute__((ext_vector_type(4))) float;

__device__ inline unsigned short f2bf(float x) {
    unsigned u = __float_as_uint(x);
    unsigned r = u + 0x7FFFu + ((u >> 16) & 1u);
    return (unsigned short)(r >> 16);
}
__device__ inline float bf2f(unsigned short h) {
    return __uint_as_float(((unsigned)h) << 16);
}

__device__ inline void gload_lds16(const void* g, void* l) {
    __builtin_amdgcn_global_load_lds(
        (const __attribute__((address_space(1))) unsigned int*)g,
        (__attribute__((address_space(3))) unsigned int*)l, 16, 0, 0);
}

// ---------------- aspect flags ----------------
__global__ void k_flag2(const int* __restrict__ asp, unsigned char* __restrict__ flags2,
                        int* __restrict__ flags1) {
    int i = blockIdx.x * blockDim.x + threadIdx.x;
    if (i < NA) {
        int n = asp[i];
        flags2[n] = 1;
        flags1[n] = 1;
    }
}

// ---------------- fused dual hierarchical exclusive scan (+ dis) ----------------
__global__ __launch_bounds__(1024) void k_scan2_local(const int* __restrict__ degi,
                                                      const int* __restrict__ flags1,
                                                      int* __restrict__ off,
                                                      int* __restrict__ off2,
                                                      int* __restrict__ blksum,
                                                      int* __restrict__ blksum2,
                                                      float* __restrict__ dis) {
    __shared__ int sh[1024];
    __shared__ int sh2[1024];
    int t = threadIdx.x;
    int base = blockIdx.x * 1024;
    int ok = (base + t < NN);
    int f = ok ? flags1[base + t] : 0;
    int d = ok ? degi[base + t] : 0;
    int v = f ? d : 0;
    if (ok) dis[base + t] = rsqrtf((float)d + 1.0f);   // +1 self loop (folded k_dis)
    sh[t] = v;
    sh2[t] = f;
    __syncthreads();
    for (int s = 1; s < 1024; s <<= 1) {
        int a = (t >= s) ? sh[t - s] : 0;
        int a2 = (t >= s) ? sh2[t - s] : 0;
        __syncthreads();
        sh[t] += a;
        sh2[t] += a2;
        __syncthreads();
    }
    if (ok) {
        off[base + t] = sh[t] - v;
        off2[base + t] = sh2[t] - f;
    }
    if (t == 1023) {
        blksum[blockIdx.x] = sh[1023];
        blksum2[blockIdx.x] = sh2[1023];
    }
}

__global__ __launch_bounds__(128) void k_scan2_blk(int* __restrict__ blksum,
                                                   int* __restrict__ blksum2, int nb) {
    __shared__ int sh[128];
    __shared__ int sh2[128];
    int t = threadIdx.x;
    int v = (t < nb) ? blksum[t] : 0;
    int v2 = (t < nb) ? blksum2[t] : 0;
    sh[t] = v;
    sh2[t] = v2;
    __syncthreads();
    for (int s = 1; s < 128; s <<= 1) {
        int a = (t >= s) ? sh[t - s] : 0;
        int a2 = (t >= s) ? sh2[t - s] : 0;
        __syncthreads();
        sh[t] += a;
        sh2[t] += a2;
        __syncthreads();
    }
    if (t < nb) {
        blksum[t] = sh[t] - v;
        blksum2[t] = sh2[t] - v2;
    }
}

// scan finalize + compact (folded k_compact)
__global__ void k_scan2_add(int* __restrict__ off, int* __restrict__ off2,
                            const int* __restrict__ blksum, const int* __restrict__ blksum2,
                            const int* __restrict__ flags1,
                            int* __restrict__ list, int* __restrict__ remap,
                            int* __restrict__ nf) {
    int i = blockIdx.x * blockDim.x + threadIdx.x;
    if (i < NN) {
        off[i] += blksum[i >> 10];
        int o2 = off2[i] + blksum2[i >> 10];
        off2[i] = o2;
        int f = flags1[i];
        if (f && o2 < NF_CAP) {
            list[o2] = i;
            remap[i] = o2;
        }
        if (i == NN - 1) {
            int tot = o2 + f;
            *nf = (tot < NF_CAP) ? tot : NF_CAP;
        }
    }
}

// ---------------- B pre-pack: fragment-ordered 16KB tile images ----------------
__global__ void k_prepB(const float* __restrict__ B, unsigned short* __restrict__ img,
                        int K, int NT) {
    int i = blockIdx.x * blockDim.x + threadIdx.x;
    if (i >= NT * 4096) return;
    int kt = i >> 12;
    int rem = i & 4095;
    int ct = rem >> 9;
    int s = rem & 511;          // lg*128 + lr*8 + j
    int lg = s >> 7;
    int lr = (s >> 3) & 15;
    int j = s & 7;
    int k = kt * 32 + lg * 8 + j;
    int col = ct * 16 + lr;
    float v = (k < K) ? B[k * 128 + col] : 0.f;
    unsigned short hi = f2bf(v);
    unsigned short lo = f2bf(v - bf2f(hi));
    img[kt * 8192 + ct * 1024 + s] = hi;
    img[kt * 8192 + ct * 1024 + 512 + s] = lo;
}

// ---------------- split-bf16 MFMA GEMM device body (round-14 structure) ----------------
// 128x128 tile, 8 waves (512 thr), wave owns 16 rows. B fragment-image DMA via
// global_load_lds (lane-linear, conflict-free, measured 0), 1-kt 32KB dbuf;
// A per-lane direct global, reg dbuf; one barrier per kt. Best measured form
// (rounds 13-21: six distinct restructures all neutral or regressed).
template <int K, int NT>
__device__ __forceinline__ void gemm_dev(int gbid, const float* __restrict__ A,
        const unsigned short* __restrict__ Bimg,
        float* __restrict__ C, int M, const int* __restrict__ Mptr) {
    __shared__ alignas(16) unsigned short ldsB[2][8192];   // 2 x 16KB
    const int Mv = Mptr ? *Mptr : M;
    const int row0 = gbid * 128;
    if (row0 >= Mv) return;
    const int t = threadIdx.x;
    const int w = t >> 6;       // 0..7
    const int l = t & 63;
    const int lr = l & 15;
    const int lg = l >> 4;

    const int r0 = row0 + w * 16 + lr;
    const long a0 = (long)(r0 < Mv ? r0 : Mv - 1) * K + lg * 8;   // clamp loads, guard stores

    f32x4 acc[8];
#pragma unroll
    for (int ct = 0; ct < 8; ++ct) acc[ct] = (f32x4){0.f, 0.f, 0.f, 0.f};

    float4 A0[2], A1[2];   // A fragment double-buffer; literal indices only

    auto LOADA = [&](float4* buf, int kt) {
        const int k0 = kt * 32 + lg * 8;
        const float* s0 = A + a0 + kt * 32;
        if (k0 + 8 <= K) {
            buf[0] = *(const float4*)(s0);
            buf[1] = *(const float4*)(s0 + 4);
        } else {
            float t0[8];
#pragma unroll
            for (int j = 0; j < 8; ++j) t0[j] = (k0 + j < K) ? s0[j] : 0.f;
            buf[0] = make_float4(t0[0], t0[1], t0[2], t0[3]);
            buf[1] = make_float4(t0[4], t0[5], t0[6], t0[7]);
        }
    };

    auto STAGE_B = [&](int buf, int kt) {   // 8 waves x 2KB = 16KB, lane-linear
        const char* g = (const char*)Bimg + (long)kt * 16384 + w * 2048 + l * 16;
        gload_lds16(g, &ldsB[buf][w * 1024]);
        gload_lds16(g + 1024, &ldsB[buf][w * 1024 + 512]);
    };

    auto CONV = [&](const float4* buf, short8& h0, short8& e0) {
        float v0[8] = {buf[0].x, buf[0].y, buf[0].z, buf[0].w, buf[1].x, buf[1].y, buf[1].z, buf[1].w};
#pragma unroll
        for (int j = 0; j < 8; ++j) {
            unsigned short hi = f2bf(v0[j]);
            h0[j] = (short)hi;
            e0[j] = (short)f2bf(v0[j] - bf2f(hi));
        }
    };

    auto COMPUTE = [&](const unsigned short* bbuf, short8 ah, short8 al) {
#pragma unroll
        for (int ct = 0; ct < 8; ++ct) {
            const unsigned short* bp = bbuf + ct * 1024 + lg * 128 + lr * 8;   // lane-linear: conflict-free
            short8 bh = *(const short8*)(bp);
            short8 bl = *(const short8*)(bp + 512);
            acc[ct] = __builtin_amdgcn_mfma_f32_16x16x32_bf16(ah, bh, acc[ct], 0, 0, 0);
            acc[ct] = __builtin_amdgcn_mfma_f32_16x16x32_bf16(al, bh, acc[ct], 0, 0, 0);
            acc[ct] = __builtin_amdgcn_mfma_f32_16x16x32_bf16(ah, bl, acc[ct], 0, 0, 0);
        }
    };

    LOADA(A0, 0);
    STAGE_B(0, 0);
    __syncthreads();   // compiler drains vmcnt before barrier -> buf0 ready
    for (int kt = 0; kt < NT; kt += 2) {
        if (kt + 1 < NT) {
            LOADA(A1, kt + 1);      // next A in flight under compute
            STAGE_B(1, kt + 1);     // next B DMA in flight under compute
        }
        {
            short8 h0, e0;
            CONV(A0, h0, e0);
            COMPUTE(ldsB[0], h0, e0);
        }
        __syncthreads();            // buf1 staged + buf0 reads done
        if (kt + 1 < NT) {
            if (kt + 2 < NT) {
                LOADA(A0, kt + 2);
                STAGE_B(0, kt + 2);
            }
            short8 h0, e0;
            CONV(A1, h0, e0);
            COMPUTE(ldsB[1], h0, e0);
            __syncthreads();
        }
    }
    // C/D layout: col = lane&15, row = (lane>>4)*4 + reg
#pragma unroll
    for (int ct = 0; ct < 8; ++ct)
#pragma unroll
        for (int r = 0; r < 4; ++r) {
            int row = row0 + w * 16 + lg * 4 + r;
            if (row < Mv) C[(long)row * 128 + ct * 16 + lr] = acc[ct][r];
        }
}

// ---------------- fused dispatch A: XCD-partitioned GEMM1-half ∥ deg_mark ----------------
// blockIdx%8 tracks the round-robin XCD assignment. XCDs 0-3 run GEMM blocks
// (Bimg stays resident in their L2s, undisturbed by edge streams); XCDs 4-7 run
// the edge pass (streaming reads + atomics contained to their own L2s).
__global__ __launch_bounds__(512, 4) void k_fusedA(const float* __restrict__ A,
        const unsigned short* __restrict__ Bimg, float* __restrict__ C,
        const int* __restrict__ src, const int* __restrict__ dst,
        const unsigned char* __restrict__ flags2,
        int* __restrict__ degi, int* __restrict__ flags1) {
    const int xcd = blockIdx.x & 7;
    const int slot = (blockIdx.x >> 3) * 4 + (xcd & 3);
    if (xcd < 4) {
        if (slot < G1_BLOCKS)
            gemm_dev<IN_DIM, 10>(slot, A, Bimg, C, NN, nullptr);
    } else {
        int e = slot * 512 + threadIdx.x;
        if (slot < EDGE_SLOTS && e < NE) {
            int d = dst[e];
            atomicAdd(&degi[d], 1);
            if (flags2[d]) flags1[src[e]] = 1;
        }
    }
}

// ---------------- fused dispatch B: XCD-partitioned GEMM1-half ∥ filtered fill ----------------
__global__ __launch_bounds__(512, 4) void k_fusedB(const float* __restrict__ A,
        const unsigned short* __restrict__ Bimg, float* __restrict__ C,
        const int* __restrict__ src, const int* __restrict__ dst,
        const int* __restrict__ flags1,
        int* __restrict__ off, int* __restrict__ csr) {
    const int xcd = blockIdx.x & 7;
    const int slot = (blockIdx.x >> 3) * 4 + (xcd & 3);
    if (xcd < 4) {
        if (slot < G1_BLOCKS)
            gemm_dev<IN_DIM, 10>(slot + G1_BLOCKS, A, Bimg, C, NN, nullptr);
    } else {
        int e = slot * 512 + threadIdx.x;
        if (slot < EDGE_SLOTS && e < NE) {
            int d = dst[e];
            if (flags1[d]) {
                int pos = atomicAdd(&off[d], 1);
                csr[pos] = src[e];
            }
        }
    }
}

// ---------------- GEMM2 (frontier rows) ----------------
__global__ __launch_bounds__(512, 4) void k_gemm2(const float* __restrict__ A,
        const unsigned short* __restrict__ Bimg, float* __restrict__ C,
        const int* __restrict__ nf) {
    gemm_dev<HID, 4>(blockIdx.x, A, Bimg, C, 0, nf);
}

// ---------------- gather layer 1: half-wave edge-parallel, float4, x2 unroll ----------------
__global__ __launch_bounds__(256) void k_gather1(const int* __restrict__ list,
                                                 const int* __restrict__ nf,
                                                 const int* __restrict__ csr,
                                                 const int* __restrict__ offpost,
                                                 const float* __restrict__ dis,
                                                 const float* __restrict__ h1,
                                                 const float* __restrict__ b1,
                                                 float* __restrict__ out) {
    int wave = threadIdx.x >> 6;
    int lane = threadIdx.x & 63;
    int half = lane >> 5;
    int sl = lane & 31;
    int idx = blockIdx.x * 4 + wave;
    if (idx >= *nf) return;
    int n = list[idx];
    int start = (n == 0) ? 0 : offpost[n - 1];
    int end = offpost[n];
    float dn = dis[n];
    float ax = 0.f, ay = 0.f, az = 0.f, aw = 0.f;
    int i = start + half;
    for (; i + 2 < end; i += 4) {          // two edges per half per trip
        int s0 = csr[i], s1 = csr[i + 2];
        float w0 = dis[s0], w1 = dis[s1];
        float4 v0 = *(const float4*)&h1[(long)s0 * HID + sl * 4];
        float4 v1 = *(const float4*)&h1[(long)s1 * HID + sl * 4];
        ax += w0 * v0.x + w1 * v1.x;
        ay += w0 * v0.y + w1 * v1.y;
        az += w0 * v0.z + w1 * v1.z;
        aw += w0 * v0.w + w1 * v1.w;
    }
    if (i < end) {
        int s = csr[i];
        float wgt = dis[s];
        float4 v = *(const float4*)&h1[(long)s * HID + sl * 4];
        ax += wgt * v.x;
        ay += wgt * v.y;
        az += wgt * v.z;
        aw += wgt * v.w;
    }
    ax += __shfl_xor(ax, 32);
    ay += __shfl_xor(ay, 32);
    az += __shfl_xor(az, 32);
    aw += __shfl_xor(aw, 32);
    if (half == 0) {
        float4 hv = *(const float4*)&h1[(long)n * HID + sl * 4];
        float4 bv = *(const float4*)&b1[sl * 4];
        float4 r;
        r.x = fmaxf(dn * (ax + dn * hv.x) + bv.x, 0.f);
        r.y = fmaxf(dn * (ay + dn * hv.y) + bv.y, 0.f);
        r.z = fmaxf(dn * (az + dn * hv.z) + bv.z, 0.f);
        r.w = fmaxf(dn * (aw + dn * hv.w) + bv.w, 0.f);
        *reinterpret_cast<float4*>(&out[(long)idx * HID + sl * 4]) = r;
    }
}

// ---------------- gather layer 2 (aspects, remapped) + classifier ----------------
__global__ __launch_bounds__(256) void k_gather2(const int* __restrict__ asp,
                                                 const int* __restrict__ remap,
                                                 const int* __restrict__ csr,
                                                 const int* __restrict__ offpost,
                                                 const float* __restrict__ dis,
                                                 const float* __restrict__ t2,
                                                 const float* __restrict__ b2,
                                                 const float* __restrict__ Wc,
                                                 const float* __restrict__ bc,
                                                 float* __restrict__ out) {
    int wave = threadIdx.x >> 6;
    int lane = threadIdx.x & 63;
    int a = blockIdx.x * 4 + wave;
    if (a >= NA) return;
    int n = asp[a];
    int start = (n == 0) ? 0 : offpost[n - 1];
    int end = offpost[n];
    float dn = dis[n];
    float ax = 0.f, ay = 0.f;
    int i = start;
    for (; i + 4 <= end; i += 4) {
        int s0 = csr[i], s1 = csr[i + 1], s2 = csr[i + 2], s3 = csr[i + 3];
        float w0 = dis[s0], w1 = dis[s1], w2 = dis[s2], w3 = dis[s3];
        int r0 = remap[s0], r1 = remap[s1], r2 = remap[s2], r3 = remap[s3];
        float2 v0 = *(const float2*)&t2[(long)r0 * HID + lane * 2];
        float2 v1 = *(const float2*)&t2[(long)r1 * HID + lane * 2];
        float2 v2 = *(const float2*)&t2[(long)r2 * HID + lane * 2];
        float2 v3 = *(const float2*)&t2[(long)r3 * HID + lane * 2];
        ax += w0 * v0.x + w1 * v1.x + w2 * v2.x + w3 * v3.x;
        ay += w0 * v0.y + w1 * v1.y + w2 * v2.y + w3 * v3.y;
    }
    for (; i < end; ++i) {
        int s = csr[i];
        float w = dis[s];
        float2 v = *(const float2*)&t2[(long)remap[s] * HID + lane * 2];
        ax += w * v.x;
        ay += w * v.y;
    }
    float2 hv = *(const float2*)&t2[(long)remap[n] * HID + lane * 2];
    float vx = dn * (ax + dn * hv.x) + b2[2 * lane];
    float vy = dn * (ay + dn * hv.y) + b2[2 * lane + 1];
    float l0 = vx * Wc[(2 * lane) * 3 + 0] + vy * Wc[(2 * lane + 1) * 3 + 0];
    float l1 = vx * Wc[(2 * lane) * 3 + 1] + vy * Wc[(2 * lane + 1) * 3 + 1];
    float l2 = vx * Wc[(2 * lane) * 3 + 2] + vy * Wc[(2 * lane + 1) * 3 + 2];
#pragma unroll
    for (int s = 32; s > 0; s >>= 1) {
        l0 += __shfl_xor(l0, s);
        l1 += __shfl_xor(l1, s);
        l2 += __shfl_xor(l2, s);
    }
    if (lane == 0) {
        out[a * 3 + 0] = l0 + bc[0];
        out[a * 3 + 1] = l1 + bc[1];
        out[a * 3 + 2] = l2 + bc[2];
    }
}

extern "C" void kernel_launch(void* const* d_in, const int* in_sizes, int n_in,
                              void* d_out, int out_size, void* d_ws, size_t ws_size,
                              hipStream_t stream) {
    const float* features = (const float*)d_in[0];
    const int* ei = (const int*)d_in[1];
    const int* src = ei;
    const int* dst = ei + NE;
    const int* asp = (const int*)d_in[2];
    const float* W1 = (const float*)d_in[3];
    const float* b1 = (const float*)d_in[4];
    const float* W2 = (const float*)d_in[5];
    const float* b2 = (const float*)d_in[6];
    const float* Wc = (const float*)d_in[7];
    const float* bc = (const float*)d_in[8];
    float* out = (float*)d_out;

    char* ws = (char*)d_ws;
    float* dis   = (float*)(ws + 0);                        // 400000
    unsigned short* bimg1 = (unsigned short*)(ws + 400384); // 163840
    unsigned short* bimg2 = (unsigned short*)(ws + 400384 + 163840); // 65536
    int*   off   = (int*)  (ws + 800768);                   // 400000 (filtered CSR offsets -> offpost)
    int*   blksum  = (int*)(ws + 1201152);                  // 1024
    int*   blksum2 = (int*)(ws + 1202176);                  // 1024
    int*   nf    = (int*)  (ws + 1203200);                  // 128
    int*   csr   = (int*)  (ws + 1203328);                  // 6400000 (ends 7603328)
    int*   flags1= (int*)  (ws + 7603328);                  // 400000
    int*   off2  = (int*)  (ws + 8003328);                  // 400000
    int*   list  = (int*)  (ws + 8403328);                  // 400000
    int*   remap = (int*)  (ws + 8803328);                  // 400000 (ends 9203328)
    float* bufA  = (float*)(ws + 9203328);                  // 51200000 (h1, then t2_c)
    float* bufB  = (float*)(ws + 60403328);                 // 25600000 (h2in_c)
    int*   degi  = (int*)  (ws + 60403328);                 // aliases bufB head: degi is
                                                            //  dead before gather1 writes bufB
    unsigned char* flags2 = (unsigned char*)(ws + 86003328);// 100000

    const int NB = (NN + 1023) / 1024;  // 98

    // prologue: flags, degree init, B pre-pack (all independent of edge pass)
    hipMemsetAsync(degi, 0, NN * sizeof(int), stream);
    hipMemsetAsync(flags1, 0, NN * sizeof(int), stream);
    hipMemsetAsync(flags2, 0, NN, stream);
    k_flag2<<<(NA + 255) / 256, 256, 0, stream>>>(asp, flags2, flags1);
    k_prepB<<<(10 * 4096 + 255) / 256, 256, 0, stream>>>(W1, bimg1, IN_DIM, 10);
    k_prepB<<<(4 * 4096 + 255) / 256, 256, 0, stream>>>(W2, bimg2, HID, 4);

    // dispatch A: XCD-partitioned GEMM1 first half ∥ deg_mark edge pass
    k_fusedA<<<FUSE_GROUPS * 8, 512, 0, stream>>>(
        features, bimg1, bufA, src, dst, flags2, degi, flags1);

    // scans (dis folded into local; compact folded into add)
    k_scan2_local<<<NB, 1024, 0, stream>>>(degi, flags1, off, off2, blksum, blksum2, dis);
    k_scan2_blk<<<1, 128, 0, stream>>>(blksum, blksum2, NB);
    k_scan2_add<<<(NN + 255) / 256, 256, 0, stream>>>(off, off2, blksum, blksum2,
                                                      flags1, list, remap, nf);

    // dispatch B: XCD-partitioned GEMM1 second half ∥ filtered CSR fill
    k_fusedB<<<FUSE_GROUPS * 8, 512, 0, stream>>>(
        features, bimg1, bufA, src, dst, flags1, off, csr);

    // layer-1 aggregation (frontier) -> compacted h2in
    k_gather1<<<(NF_CAP + 3) / 4, 256, 0, stream>>>(list, nf, csr, off, dis, bufA, b1, bufB);

    // layer 2: t2_c = h2in_c@W2 (frontier rows); logits per aspect
    k_gemm2<<<(NF_CAP + 127) / 128, 512, 0, stream>>>(bufB, bimg2, bufA, nf);
    k_gather2<<<(NA + 3) / 4, 256, 0, stream>>>(asp, remap, csr, off, dis, bufA, b2, Wc, bc, out);
}

// Round 23
// 198.643 us; speedup vs baseline: 1.1052x; 1.0173x over previous
//
#include <hip/hip_runtime.h>

constexpr int NN = 100000;
constexpr int NE = 1600000;
constexpr int IN_DIM = 300;
constexpr int HID = 128;
constexpr int NA = 2048;
constexpr int NF_CAP = 50000;   // frontier cap (expected ~29K for this input)
constexpr int G1_BLOCKS = 391;  // ceil(782/2): GEMM1 half-grid per fused dispatch
constexpr int EDGE_BLOCKS = 3125;  // NE / 512 exactly (dispatch B, interleaved)
constexpr int EDGE_SLOTS = 3125;   // dispatch A slots
constexpr int FUSE_GROUPS = 782;   // ceil(EDGE_SLOTS/4): 8-block groups (4 gemm-lane, 4 edge-lane)

using short8 = __attribute__((ext_vector_type(8))) short;
using f32x4  = __attribute__((ext_vector_type(4))) float;

__device__ inline unsigned short f2bf(float x) {
    unsigned u = __float_as_uint(x);
    unsigned r = u + 0x7FFFu + ((u >> 16) & 1u);
    return (unsigned short)(r >> 16);
}
__device__ inline float bf2f(unsigned short h) {
    return __uint_as_float(((unsigned)h) << 16);
}

__device__ inline void gload_lds16(const void* g, void* l) {
    __builtin_amdgcn_global_load_lds(
        (const __attribute__((address_space(1))) unsigned int*)g,
        (__attribute__((address_space(3))) unsigned int*)l, 16, 0, 0);
}

// ---------------- aspect flags ----------------
__global__ void k_flag2(const int* __restrict__ asp, unsigned char* __restrict__ flags2,
                        int* __restrict__ flags1) {
    int i = blockIdx.x * blockDim.x + threadIdx.x;
    if (i < NA) {
        int n = asp[i];
        flags2[n] = 1;
        flags1[n] = 1;
    }
}

// ---------------- fused dual hierarchical exclusive scan (+ dis) ----------------
__global__ __launch_bounds__(1024) void k_scan2_local(const int* __restrict__ degi,
                                                      const int* __restrict__ flags1,
                                                      int* __restrict__ off,
                                                      int* __restrict__ off2,
                                                      int* __restrict__ blksum,
                                                      int* __restrict__ blksum2,
                                                      float* __restrict__ dis) {
    __shared__ int sh[1024];
    __shared__ int sh2[1024];
    int t = threadIdx.x;
    int base = blockIdx.x * 1024;
    int ok = (base + t < NN);
    int f = ok ? flags1[base + t] : 0;
    int d = ok ? degi[base + t] : 0;
    int v = f ? d : 0;
    if (ok) dis[base + t] = rsqrtf((float)d + 1.0f);   // +1 self loop (folded k_dis)
    sh[t] = v;
    sh2[t] = f;
    __syncthreads();
    for (int s = 1; s < 1024; s <<= 1) {
        int a = (t >= s) ? sh[t - s] : 0;
        int a2 = (t >= s) ? sh2[t - s] : 0;
        __syncthreads();
        sh[t] += a;
        sh2[t] += a2;
        __syncthreads();
    }
    if (ok) {
        off[base + t] = sh[t] - v;
        off2[base + t] = sh2[t] - f;
    }
    if (t == 1023) {
        blksum[blockIdx.x] = sh[1023];
        blksum2[blockIdx.x] = sh2[1023];
    }
}

__global__ __launch_bounds__(128) void k_scan2_blk(int* __restrict__ blksum,
                                                   int* __restrict__ blksum2, int nb) {
    __shared__ int sh[128];
    __shared__ int sh2[128];
    int t = threadIdx.x;
    int v = (t < nb) ? blksum[t] : 0;
    int v2 = (t < nb) ? blksum2[t] : 0;
    sh[t] = v;
    sh2[t] = v2;
    __syncthreads();
    for (int s = 1; s < 128; s <<= 1) {
        int a = (t >= s) ? sh[t - s] : 0;
        int a2 = (t >= s) ? sh2[t - s] : 0;
        __syncthreads();
        sh[t] += a;
        sh2[t] += a2;
        __syncthreads();
    }
    if (t < nb) {
        blksum[t] = sh[t] - v;
        blksum2[t] = sh2[t] - v2;
    }
}

// scan finalize + compact (folded k_compact)
__global__ void k_scan2_add(int* __restrict__ off, int* __restrict__ off2,
                            const int* __restrict__ blksum, const int* __restrict__ blksum2,
                            const int* __restrict__ flags1,
                            int* __restrict__ list, int* __restrict__ remap,
                            int* __restrict__ nf) {
    int i = blockIdx.x * blockDim.x + threadIdx.x;
    if (i < NN) {
        off[i] += blksum[i >> 10];
        int o2 = off2[i] + blksum2[i >> 10];
        off2[i] = o2;
        int f = flags1[i];
        if (f && o2 < NF_CAP) {
            list[o2] = i;
            remap[i] = o2;
        }
        if (i == NN - 1) {
            int tot = o2 + f;
            *nf = (tot < NF_CAP) ? tot : NF_CAP;
        }
    }
}

// ---------------- B pre-pack: fragment-ordered 16KB tile images ----------------
__global__ void k_prepB(const float* __restrict__ B, unsigned short* __restrict__ img,
                        int K, int NT) {
    int i = blockIdx.x * blockDim.x + threadIdx.x;
    if (i >= NT * 4096) return;
    int kt = i >> 12;
    int rem = i & 4095;
    int ct = rem >> 9;
    int s = rem & 511;          // lg*128 + lr*8 + j
    int lg = s >> 7;
    int lr = (s >> 3) & 15;
    int j = s & 7;
    int k = kt * 32 + lg * 8 + j;
    int col = ct * 16 + lr;
    float v = (k < K) ? B[k * 128 + col] : 0.f;
    unsigned short hi = f2bf(v);
    unsigned short lo = f2bf(v - bf2f(hi));
    img[kt * 8192 + ct * 1024 + s] = hi;
    img[kt * 8192 + ct * 1024 + 512 + s] = lo;
}

// ---------------- split-bf16 MFMA GEMM device body (round-14 structure) ----------------
// 128x128 tile, 8 waves (512 thr), wave owns 16 rows. B fragment-image DMA via
// global_load_lds (lane-linear, conflict-free, measured 0), 1-kt 32KB dbuf;
// A per-lane direct global, reg dbuf; one barrier per kt. Best measured form.
template <int K, int NT>
__device__ __forceinline__ void gemm_dev(int gbid, const float* __restrict__ A,
        const unsigned short* __restrict__ Bimg,
        float* __restrict__ C, int M, const int* __restrict__ Mptr) {
    __shared__ alignas(16) unsigned short ldsB[2][8192];   // 2 x 16KB
    const int Mv = Mptr ? *Mptr : M;
    const int row0 = gbid * 128;
    if (row0 >= Mv) return;
    const int t = threadIdx.x;
    const int w = t >> 6;       // 0..7
    const int l = t & 63;
    const int lr = l & 15;
    const int lg = l >> 4;

    const int r0 = row0 + w * 16 + lr;
    const long a0 = (long)(r0 < Mv ? r0 : Mv - 1) * K + lg * 8;   // clamp loads, guard stores

    f32x4 acc[8];
#pragma unroll
    for (int ct = 0; ct < 8; ++ct) acc[ct] = (f32x4){0.f, 0.f, 0.f, 0.f};

    float4 A0[2], A1[2];   // A fragment double-buffer; literal indices only

    auto LOADA = [&](float4* buf, int kt) {
        const int k0 = kt * 32 + lg * 8;
        const float* s0 = A + a0 + kt * 32;
        if (k0 + 8 <= K) {
            buf[0] = *(const float4*)(s0);
            buf[1] = *(const float4*)(s0 + 4);
        } else {
            float t0[8];
#pragma unroll
            for (int j = 0; j < 8; ++j) t0[j] = (k0 + j < K) ? s0[j] : 0.f;
            buf[0] = make_float4(t0[0], t0[1], t0[2], t0[3]);
            buf[1] = make_float4(t0[4], t0[5], t0[6], t0[7]);
        }
    };

    auto STAGE_B = [&](int buf, int kt) {   // 8 waves x 2KB = 16KB, lane-linear
        const char* g = (const char*)Bimg + (long)kt * 16384 + w * 2048 + l * 16;
        gload_lds16(g, &ldsB[buf][w * 1024]);
        gload_lds16(g + 1024, &ldsB[buf][w * 1024 + 512]);
    };

    auto CONV = [&](const float4* buf, short8& h0, short8& e0) {
        float v0[8] = {buf[0].x, buf[0].y, buf[0].z, buf[0].w, buf[1].x, buf[1].y, buf[1].z, buf[1].w};
#pragma unroll
        for (int j = 0; j < 8; ++j) {
            unsigned short hi = f2bf(v0[j]);
            h0[j] = (short)hi;
            e0[j] = (short)f2bf(v0[j] - bf2f(hi));
        }
    };

    auto COMPUTE = [&](const unsigned short* bbuf, short8 ah, short8 al) {
#pragma unroll
        for (int ct = 0; ct < 8; ++ct) {
            const unsigned short* bp = bbuf + ct * 1024 + lg * 128 + lr * 8;   // lane-linear: conflict-free
            short8 bh = *(const short8*)(bp);
            short8 bl = *(const short8*)(bp + 512);
            acc[ct] = __builtin_amdgcn_mfma_f32_16x16x32_bf16(ah, bh, acc[ct], 0, 0, 0);
            acc[ct] = __builtin_amdgcn_mfma_f32_16x16x32_bf16(al, bh, acc[ct], 0, 0, 0);
            acc[ct] = __builtin_amdgcn_mfma_f32_16x16x32_bf16(ah, bl, acc[ct], 0, 0, 0);
        }
    };

    LOADA(A0, 0);
    STAGE_B(0, 0);
    __syncthreads();   // compiler drains vmcnt before barrier -> buf0 ready
    for (int kt = 0; kt < NT; kt += 2) {
        if (kt + 1 < NT) {
            LOADA(A1, kt + 1);      // next A in flight under compute
            STAGE_B(1, kt + 1);     // next B DMA in flight under compute
        }
        {
            short8 h0, e0;
            CONV(A0, h0, e0);
            COMPUTE(ldsB[0], h0, e0);
        }
        __syncthreads();            // buf1 staged + buf0 reads done
        if (kt + 1 < NT) {
            if (kt + 2 < NT) {
                LOADA(A0, kt + 2);
                STAGE_B(0, kt + 2);
            }
            short8 h0, e0;
            CONV(A1, h0, e0);
            COMPUTE(ldsB[1], h0, e0);
            __syncthreads();
        }
    }
    // C/D layout: col = lane&15, row = (lane>>4)*4 + reg
#pragma unroll
    for (int ct = 0; ct < 8; ++ct)
#pragma unroll
        for (int r = 0; r < 4; ++r) {
            int row = row0 + w * 16 + lg * 4 + r;
            if (row < Mv) C[(long)row * 128 + ct * 16 + lr] = acc[ct][r];
        }
}

// ---------------- fused dispatch A (XCD-partitioned, round-22 measured 79us) ----------------
// XCDs 0-3 run GEMM1 first half (Bimg L2-resident, undisturbed); XCDs 4-7 run
// the deg_mark edge pass (streams + atomics contained to their own L2s).
__global__ __launch_bounds__(512, 4) void k_fusedA(const float* __restrict__ A,
        const unsigned short* __restrict__ Bimg, float* __restrict__ C,
        const int* __restrict__ src, const int* __restrict__ dst,
        const unsigned char* __restrict__ flags2,
        int* __restrict__ degi, int* __restrict__ flags1) {
    const int xcd = blockIdx.x & 7;
    const int slot = (blockIdx.x >> 3) * 4 + (xcd & 3);
    if (xcd < 4) {
        if (slot < G1_BLOCKS)
            gemm_dev<IN_DIM, 10>(slot, A, Bimg, C, NN, nullptr);
    } else {
        int e = slot * 512 + threadIdx.x;
        if (slot < EDGE_SLOTS && e < NE) {
            int d = dst[e];
            atomicAdd(&degi[d], 1);
            if (flags2[d]) flags1[src[e]] = 1;
        }
    }
}

// ---------------- fused dispatch B (interleaved, round-15 measured ~80us) ----------------
// GEMM blocks at low IDs (launch first), edge blocks stream after; full-machine
// sharing measured best for the heavier fill pass (round-22 partition was worse).
__global__ __launch_bounds__(512, 4) void k_fusedB(const float* __restrict__ A,
        const unsigned short* __restrict__ Bimg, float* __restrict__ C,
        const int* __restrict__ src, const int* __restrict__ dst,
        const int* __restrict__ flags1,
        int* __restrict__ off, int* __restrict__ csr) {
    if (blockIdx.x < G1_BLOCKS) {
        gemm_dev<IN_DIM, 10>(blockIdx.x + G1_BLOCKS, A, Bimg, C, NN, nullptr);
    } else {
        int e = (blockIdx.x - G1_BLOCKS) * 512 + threadIdx.x;
        if (e < NE) {
            int d = dst[e];
            if (flags1[d]) {
                int pos = atomicAdd(&off[d], 1);
                csr[pos] = src[e];
            }
        }
    }
}

// ---------------- GEMM2 (frontier rows) ----------------
__global__ __launch_bounds__(512, 4) void k_gemm2(const float* __restrict__ A,
        const unsigned short* __restrict__ Bimg, float* __restrict__ C,
        const int* __restrict__ nf) {
    gemm_dev<HID, 4>(blockIdx.x, A, Bimg, C, 0, nf);
}

// ---------------- gather layer 1: half-wave edge-parallel, float4, x2 unroll ----------------
__global__ __launch_bounds__(256) void k_gather1(const int* __restrict__ list,
                                                 const int* __restrict__ nf,
                                                 const int* __restrict__ csr,
                                                 const int* __restrict__ offpost,
                                                 const float* __restrict__ dis,
                                                 const float* __restrict__ h1,
                                                 const float* __restrict__ b1,
                                                 float* __restrict__ out) {
    int wave = threadIdx.x >> 6;
    int lane = threadIdx.x & 63;
    int half = lane >> 5;
    int sl = lane & 31;
    int idx = blockIdx.x * 4 + wave;
    if (idx >= *nf) return;
    int n = list[idx];
    int start = (n == 0) ? 0 : offpost[n - 1];
    int end = offpost[n];
    float dn = dis[n];
    float ax = 0.f, ay = 0.f, az = 0.f, aw = 0.f;
    int i = start + half;
    for (; i + 2 < end; i += 4) {          // two edges per half per trip
        int s0 = csr[i], s1 = csr[i + 2];
        float w0 = dis[s0], w1 = dis[s1];
        float4 v0 = *(const float4*)&h1[(long)s0 * HID + sl * 4];
        float4 v1 = *(const float4*)&h1[(long)s1 * HID + sl * 4];
        ax += w0 * v0.x + w1 * v1.x;
        ay += w0 * v0.y + w1 * v1.y;
        az += w0 * v0.z + w1 * v1.z;
        aw += w0 * v0.w + w1 * v1.w;
    }
    if (i < end) {
        int s = csr[i];
        float wgt = dis[s];
        float4 v = *(const float4*)&h1[(long)s * HID + sl * 4];
        ax += wgt * v.x;
        ay += wgt * v.y;
        az += wgt * v.z;
        aw += wgt * v.w;
    }
    ax += __shfl_xor(ax, 32);
    ay += __shfl_xor(ay, 32);
    az += __shfl_xor(az, 32);
    aw += __shfl_xor(aw, 32);
    if (half == 0) {
        float4 hv = *(const float4*)&h1[(long)n * HID + sl * 4];
        float4 bv = *(const float4*)&b1[sl * 4];
        float4 r;
        r.x = fmaxf(dn * (ax + dn * hv.x) + bv.x, 0.f);
        r.y = fmaxf(dn * (ay + dn * hv.y) + bv.y, 0.f);
        r.z = fmaxf(dn * (az + dn * hv.z) + bv.z, 0.f);
        r.w = fmaxf(dn * (aw + dn * hv.w) + bv.w, 0.f);
        *reinterpret_cast<float4*>(&out[(long)idx * HID + sl * 4]) = r;
    }
}

// ---------------- gather layer 2 (aspects, remapped) + classifier ----------------
__global__ __launch_bounds__(256) void k_gather2(const int* __restrict__ asp,
                                                 const int* __restrict__ remap,
                                                 const int* __restrict__ csr,
                                                 const int* __restrict__ offpost,
                                                 const float* __restrict__ dis,
                                                 const float* __restrict__ t2,
                                                 const float* __restrict__ b2,
                                                 const float* __restrict__ Wc,
                                                 const float* __restrict__ bc,
                                                 float* __restrict__ out) {
    int wave = threadIdx.x >> 6;
    int lane = threadIdx.x & 63;
    int a = blockIdx.x * 4 + wave;
    if (a >= NA) return;
    int n = asp[a];
    int start = (n == 0) ? 0 : offpost[n - 1];
    int end = offpost[n];
    float dn = dis[n];
    float ax = 0.f, ay = 0.f;
    int i = start;
    for (; i + 4 <= end; i += 4) {
        int s0 = csr[i], s1 = csr[i + 1], s2 = csr[i + 2], s3 = csr[i + 3];
        float w0 = dis[s0], w1 = dis[s1], w2 = dis[s2], w3 = dis[s3];
        int r0 = remap[s0], r1 = remap[s1], r2 = remap[s2], r3 = remap[s3];
        float2 v0 = *(const float2*)&t2[(long)r0 * HID + lane * 2];
        float2 v1 = *(const float2*)&t2[(long)r1 * HID + lane * 2];
        float2 v2 = *(const float2*)&t2[(long)r2 * HID + lane * 2];
        float2 v3 = *(const float2*)&t2[(long)r3 * HID + lane * 2];
        ax += w0 * v0.x + w1 * v1.x + w2 * v2.x + w3 * v3.x;
        ay += w0 * v0.y + w1 * v1.y + w2 * v2.y + w3 * v3.y;
    }
    for (; i < end; ++i) {
        int s = csr[i];
        float w = dis[s];
        float2 v = *(const float2*)&t2[(long)remap[s] * HID + lane * 2];
        ax += w * v.x;
        ay += w * v.y;
    }
    float2 hv = *(const float2*)&t2[(long)remap[n] * HID + lane * 2];
    float vx = dn * (ax + dn * hv.x) + b2[2 * lane];
    float vy = dn * (ay + dn * hv.y) + b2[2 * lane + 1];
    float l0 = vx * Wc[(2 * lane) * 3 + 0] + vy * Wc[(2 * lane + 1) * 3 + 0];
    float l1 = vx * Wc[(2 * lane) * 3 + 1] + vy * Wc[(2 * lane + 1) * 3 + 1];
    float l2 = vx * Wc[(2 * lane) * 3 + 2] + vy * Wc[(2 * lane + 1) * 3 + 2];
#pragma unroll
    for (int s = 32; s > 0; s >>= 1) {
        l0 += __shfl_xor(l0, s);
        l1 += __shfl_xor(l1, s);
        l2 += __shfl_xor(l2, s);
    }
    if (lane == 0) {
        out[a * 3 + 0] = l0 + bc[0];
        out[a * 3 + 1] = l1 + bc[1];
        out[a * 3 + 2] = l2 + bc[2];
    }
}

extern "C" void kernel_launch(void* const* d_in, const int* in_sizes, int n_in,
                              void* d_out, int out_size, void* d_ws, size_t ws_size,
                              hipStream_t stream) {
    const float* features = (const float*)d_in[0];
    const int* ei = (const int*)d_in[1];
    const int* src = ei;
    const int* dst = ei + NE;
    const int* asp = (const int*)d_in[2];
    const float* W1 = (const float*)d_in[3];
    const float* b1 = (const float*)d_in[4];
    const float* W2 = (const float*)d_in[5];
    const float* b2 = (const float*)d_in[6];
    const float* Wc = (const float*)d_in[7];
    const float* bc = (const float*)d_in[8];
    float* out = (float*)d_out;

    char* ws = (char*)d_ws;
    float* dis   = (float*)(ws + 0);                        // 400000
    unsigned short* bimg1 = (unsigned short*)(ws + 400384); // 163840
    unsigned short* bimg2 = (unsigned short*)(ws + 400384 + 163840); // 65536
    int*   off   = (int*)  (ws + 800768);                   // 400000 (filtered CSR offsets -> offpost)
    int*   blksum  = (int*)(ws + 1201152);                  // 1024
    int*   blksum2 = (int*)(ws + 1202176);                  // 1024
    int*   nf    = (int*)  (ws + 1203200);                  // 128
    int*   csr   = (int*)  (ws + 1203328);                  // 6400000 (ends 7603328)
    int*   flags1= (int*)  (ws + 7603328);                  // 400000
    int*   off2  = (int*)  (ws + 8003328);                  // 400000
    int*   list  = (int*)  (ws + 8403328);                  // 400000
    int*   remap = (int*)  (ws + 8803328);                  // 400000 (ends 9203328)
    float* bufA  = (float*)(ws + 9203328);                  // 51200000 (h1, then t2_c)
    float* bufB  = (float*)(ws + 60403328);                 // 25600000 (h2in_c)
    int*   degi  = (int*)  (ws + 60403328);                 // aliases bufB head: degi is
                                                            //  dead before gather1 writes bufB
    unsigned char* flags2 = (unsigned char*)(ws + 86003328);// 100000

    const int NB = (NN + 1023) / 1024;  // 98

    // prologue: flags, degree init, B pre-pack (all independent of edge pass)
    hipMemsetAsync(degi, 0, NN * sizeof(int), stream);
    hipMemsetAsync(flags1, 0, NN * sizeof(int), stream);
    hipMemsetAsync(flags2, 0, NN, stream);
    k_flag2<<<(NA + 255) / 256, 256, 0, stream>>>(asp, flags2, flags1);
    k_prepB<<<(10 * 4096 + 255) / 256, 256, 0, stream>>>(W1, bimg1, IN_DIM, 10);
    k_prepB<<<(4 * 4096 + 255) / 256, 256, 0, stream>>>(W2, bimg2, HID, 4);

    // dispatch A: XCD-partitioned GEMM1 first half ∥ deg_mark edge pass
    k_fusedA<<<FUSE_GROUPS * 8, 512, 0, stream>>>(
        features, bimg1, bufA, src, dst, flags2, degi, flags1);

    // scans (dis folded into local; compact folded into add)
    k_scan2_local<<<NB, 1024, 0, stream>>>(degi, flags1, off, off2, blksum, blksum2, dis);
    k_scan2_blk<<<1, 128, 0, stream>>>(blksum, blksum2, NB);
    k_scan2_add<<<(NN + 255) / 256, 256, 0, stream>>>(off, off2, blksum, blksum2,
                                                      flags1, list, remap, nf);

    // dispatch B: interleaved GEMM1 second half ∥ filtered CSR fill
    k_fusedB<<<G1_BLOCKS + EDGE_BLOCKS, 512, 0, stream>>>(
        features, bimg1, bufA, src, dst, flags1, off, csr);

    // layer-1 aggregation (frontier) -> compacted h2in
    k_gather1<<<(NF_CAP + 3) / 4, 256, 0, stream>>>(list, nf, csr, off, dis, bufA, b1, bufB);

    // layer 2: t2_c = h2in_c@W2 (frontier rows); logits per aspect
    k_gemm2<<<(NF_CAP + 127) / 128, 512, 0, stream>>>(bufB, bimg2, bufA, nf);
    k_gather2<<<(NA + 3) / 4, 256, 0, stream>>>(asp, remap, csr, off, dis, bufA, b2, Wc, bc, out);
}